// Round 3
// baseline (2675.624 us; speedup 1.0000x reference)
//
#include <hip/hip_runtime.h>
#include <hip/hip_bf16.h>
#include <cstdint>
#include <cstddef>

#define V_ 8192
#define D_ 1024
#define B_ 32
#define T_ 128

typedef __attribute__((ext_vector_type(8))) short bf16x8;
typedef __attribute__((ext_vector_type(4))) float f32x4;

__device__ __forceinline__ short f2bf(float f) {
  union { float f; unsigned u; } v; v.f = f;
  unsigned r = v.u + 0x7fffu + ((v.u >> 16) & 1u);
  return (short)(r >> 16);
}

// async global->LDS, 16B per lane. lds base must be wave-uniform.
__device__ __forceinline__ void lds_load16(const void* g, void* l) {
  __builtin_amdgcn_global_load_lds(
      (const __attribute__((address_space(1))) unsigned int*)g,
      (__attribute__((address_space(3))) unsigned int*)l,
      16, 0, 0);
}

// ---------- f32 -> bf16 conversion ----------
__global__ __launch_bounds__(256) void conv_bf16_k(const float* __restrict__ in,
                                                   short* __restrict__ out, int n4) {
  int i = blockIdx.x * 256 + threadIdx.x;  // one float4 per thread
  if (i >= n4) return;
  float4 v = reinterpret_cast<const float4*>(in)[i];
  short4 o;
  o.x = f2bf(v.x); o.y = f2bf(v.y); o.z = f2bf(v.z); o.w = f2bf(v.w);
  reinterpret_cast<short4*>(out)[i] = o;
}

// ---------- W_hh split: Rb = bf16(W_hh, zero diag), Wdiag = diag(W_hh) f32 ----------
__global__ __launch_bounds__(256) void conv_whh(const float* __restrict__ W,
                                                short* __restrict__ Rb,
                                                float* __restrict__ Wdiag) {
  int i = blockIdx.x * 256 + threadIdx.x;   // over D*D = 1048576
  int n = i >> 10;
  int k = i & (D_ - 1);
  float w = W[i];
  Rb[i] = f2bf(k == n ? 0.0f : w);
  if (k == n) Wdiag[n] = w;
}

// ---------- h0 -> Hb slot0 (bf16); zero grid-barrier state ----------
__global__ __launch_bounds__(256) void init_h(const float* __restrict__ h0,
                                              short* __restrict__ Hb0,
                                              unsigned* __restrict__ bar) {
  int i = blockIdx.x * 256 + threadIdx.x;   // over 32768
  Hb0[i] = f2bf(h0[i]);
  if (i < 2) bar[i] = 0u;
}

// ---------- X[t,b,d] = W_ih[d, idx[b,t]] + b_ih[d] + b_hh[d] ----------
__global__ __launch_bounds__(256) void xgather(const int* __restrict__ idx,
                                               const float* __restrict__ W_ih,
                                               const float* __restrict__ b_ih,
                                               const float* __restrict__ b_hh,
                                               float* __restrict__ X) {
  int i = blockIdx.x * 256 + threadIdx.x;   // over T*B*D = 4194304
  int d = i & (D_ - 1);
  int b = (i >> 10) & (B_ - 1);
  int t = i >> 15;
  int tok = idx[b * T_ + t];
  X[i] = W_ih[(size_t)d * V_ + tok] + b_ih[d] + b_hh[d];
}

// ---------- persistent recurrence: all 128 steps in one kernel ----------
// h_next[m,n] = tanh(X_t[m,n] + sum_k Hb[m,k]*Rb[n,k] + hf[m,n]*Wdiag[n])
// grid 128 blocks (all co-resident on 256 CUs) x 512 thr (8 waves).
// block b: n-tile ng = b>>1 (16 n), m-tile mg = b&1 (16 m).
// wave w: K-slice [w*128, w*128+128). Rb fragments persistent in VGPRs.
// wave 0 holds the f32 diagonal state hf in registers for all 128 steps.
__global__ __launch_bounds__(512) void rnn_all(const short* __restrict__ Rb,
                                               const float* __restrict__ Wdiag,
                                               const float* __restrict__ h0,
                                               const float* __restrict__ X,
                                               short* __restrict__ Hb,
                                               unsigned* __restrict__ bar) {
  const int tid = threadIdx.x;
  const int lane = tid & 63;
  const int w = tid >> 6;                  // K-slice id, wave-uniform
  const int mg = blockIdx.x & 1;
  const int ng = blockIdx.x >> 1;
  const int m0 = mg * 16, n0 = ng * 16;
  const int fcol = lane & 15;
  const int kof = w * 128 + (lane >> 4) * 8;
  const unsigned nblk = gridDim.x;

  __shared__ f32x4 part[8][64];            // 8 KB

  // persistent B fragments: Rb rows n0..n0+15, this wave's K-slice
  bf16x8 bfrag[4];
  {
    const short* bp = Rb + (size_t)(n0 + fcol) * D_ + kof;
#pragma unroll
    for (int kk = 0; kk < 4; ++kk)
      bfrag[kk] = *reinterpret_cast<const bf16x8*>(bp + kk * 32);
  }

  // wave-0 epilogue state (registers, persistent across steps)
  float hf[4] = {0.f, 0.f, 0.f, 0.f};
  float wd = 0.f;
  const int n = n0 + fcol;
  if (w == 0) {
    wd = Wdiag[n];
#pragma unroll
    for (int q = 0; q < 4; ++q)
      hf[q] = h0[(size_t)(m0 + (lane >> 4) * 4 + q) * D_ + n];
  }

  for (int t = 0; t < T_; ++t) {
    // prefetch X_t values (no cross-step dependence)
    float xv[4] = {0.f, 0.f, 0.f, 0.f};
    if (w == 0) {
      const float* xt = X + (size_t)t * (B_ * D_);
#pragma unroll
      for (int q = 0; q < 4; ++q)
        xv[q] = xt[(size_t)(m0 + (lane >> 4) * 4 + q) * D_ + n];
    }

    // A fragments: Hb slot t, rows m0..m0+15, this wave's K-slice
    const short* ap = Hb + (size_t)t * (B_ * D_) + (size_t)(m0 + fcol) * D_ + kof;
    bf16x8 a0 = *reinterpret_cast<const bf16x8*>(ap);
    bf16x8 a1 = *reinterpret_cast<const bf16x8*>(ap + 32);
    bf16x8 a2 = *reinterpret_cast<const bf16x8*>(ap + 64);
    bf16x8 a3 = *reinterpret_cast<const bf16x8*>(ap + 96);

    f32x4 acc = {0.f, 0.f, 0.f, 0.f};
    acc = __builtin_amdgcn_mfma_f32_16x16x32_bf16(a0, bfrag[0], acc, 0, 0, 0);
    acc = __builtin_amdgcn_mfma_f32_16x16x32_bf16(a1, bfrag[1], acc, 0, 0, 0);
    acc = __builtin_amdgcn_mfma_f32_16x16x32_bf16(a2, bfrag[2], acc, 0, 0, 0);
    acc = __builtin_amdgcn_mfma_f32_16x16x32_bf16(a3, bfrag[3], acc, 0, 0, 0);

    part[w][lane] = acc;
    __syncthreads();

    if (w == 0) {
      f32x4 s = part[0][lane];
#pragma unroll
      for (int r = 1; r < 8; ++r) s += part[r][lane];
      short* hn = Hb + (size_t)(t + 1) * (B_ * D_);
#pragma unroll
      for (int q = 0; q < 4; ++q) {
        int m = m0 + (lane >> 4) * 4 + q;
        float v = tanhf(xv[q] + s[q] + hf[q] * wd);
        hf[q] = v;
        hn[(size_t)m * D_ + n] = f2bf(v);
      }
      __threadfence();   // release Hb writes to device scope (wbl2)
    }
    __syncthreads();     // wave0 done; LDS reusable

    // grid barrier (sense via generation counter)
    if (tid == 0) {
      unsigned g = __hip_atomic_load(bar + 1, __ATOMIC_RELAXED, __HIP_MEMORY_SCOPE_AGENT);
      unsigned old = __hip_atomic_fetch_add(bar, 1u, __ATOMIC_ACQ_REL, __HIP_MEMORY_SCOPE_AGENT);
      if (old == nblk - 1u) {
        __hip_atomic_store(bar, 0u, __ATOMIC_RELAXED, __HIP_MEMORY_SCOPE_AGENT);
        __hip_atomic_store(bar + 1, g + 1u, __ATOMIC_RELEASE, __HIP_MEMORY_SCOPE_AGENT);
      } else {
        while (__hip_atomic_load(bar + 1, __ATOMIC_ACQUIRE, __HIP_MEMORY_SCOPE_AGENT) == g)
          __builtin_amdgcn_s_sleep(2);
      }
    }
    __syncthreads();
    __builtin_amdgcn_fence(__ATOMIC_ACQUIRE, "agent");  // invalidate L1/L2 before reading new Hb slot
  }
}

// ---------- logits GEMM: C[r, v] = sum_d Hb[r,d]*Wb[v,d] + b_o[v] ----------
// M=4096, N=8192, K=1024. bf16 MFMA 16x16x32, tile 128x128, BK=64, 4 waves.
// LDS XOR-swizzle: chunk col ^= (row&7), applied on global SOURCE + ds_read index.
__global__ __launch_bounds__(256) void gemm_logits(const short* __restrict__ A,
                                                   const short* __restrict__ Bt,
                                                   const float* __restrict__ b_o,
                                                   float* __restrict__ C) {
  constexpr int K = D_;
  constexpr int N = V_;
  __shared__ __align__(16) short As[128 * 64];  // 16 KB, [128][8 chunks of 8 bf16]
  __shared__ __align__(16) short Bs[128 * 64];

  const int tid = threadIdx.x;
  const int lane = tid & 63;
  const int w = tid >> 6;
  const int wr = w >> 1, wc = w & 1;
  const int r0 = blockIdx.y * 128;
  const int c0 = blockIdx.x * 128;

  f32x4 acc[4][4] = {};

  for (int k0 = 0; k0 < K; k0 += 64) {
#pragma unroll
    for (int i = 0; i < 4; ++i) {
      int c = tid + 256 * i;                 // per-lane chunk id
      int cb = (tid & ~63) + 256 * i;        // wave-uniform chunk base
      int row = c >> 3;
      int colc = ((c & 7) ^ (row & 7)) * 8;  // pre-swizzled source column
      lds_load16(A + (size_t)(r0 + row) * K + k0 + colc, &As[cb * 8]);
      lds_load16(Bt + (size_t)(c0 + row) * K + k0 + colc, &Bs[cb * 8]);
    }
    asm volatile("s_waitcnt vmcnt(0)" ::: "memory");
    __syncthreads();

#pragma unroll
    for (int kk = 0; kk < 2; ++kk) {
      bf16x8 af[4], bfr[4];
      const int fcol = lane & 15;
      const int chunk = (kk * 4 + (lane >> 4)) ^ (fcol & 7);  // swizzled read chunk
#pragma unroll
      for (int i = 0; i < 4; ++i)
        af[i] = *reinterpret_cast<const bf16x8*>(&As[(wr * 64 + i * 16 + fcol) * 64 + chunk * 8]);
#pragma unroll
      for (int j = 0; j < 4; ++j)
        bfr[j] = *reinterpret_cast<const bf16x8*>(&Bs[(wc * 64 + j * 16 + fcol) * 64 + chunk * 8]);
#pragma unroll
      for (int i = 0; i < 4; ++i)
#pragma unroll
        for (int j = 0; j < 4; ++j)
          acc[i][j] = __builtin_amdgcn_mfma_f32_16x16x32_bf16(af[i], bfr[j], acc[i][j], 0, 0, 0);
    }
    __syncthreads();
  }

  const int fcol = lane & 15;
  const int frow = (lane >> 4) * 4;
#pragma unroll
  for (int i = 0; i < 4; ++i) {
    int row = r0 + wr * 64 + i * 16 + frow;
#pragma unroll
    for (int j = 0; j < 4; ++j) {
      int col = c0 + wc * 64 + j * 16 + fcol;
      float bias = b_o[col];
#pragma unroll
      for (int q = 0; q < 4; ++q)
        C[(size_t)(row + q) * N + col] = acc[i][j][q] + bias;
    }
  }
}

// ---------- in-place log-softmax over rows of 8192 ----------
__global__ __launch_bounds__(256) void logsoftmax(float* __restrict__ out) {
  __shared__ float red[4];
  __shared__ float red2[4];
  float* row = out + (size_t)blockIdx.x * V_;
  const int tid = threadIdx.x;

  float4 v[8];
  float mx = -1e30f;
#pragma unroll
  for (int i = 0; i < 8; ++i) {
    v[i] = *reinterpret_cast<const float4*>(&row[(i * 256 + tid) * 4]);
    mx = fmaxf(mx, fmaxf(fmaxf(v[i].x, v[i].y), fmaxf(v[i].z, v[i].w)));
  }
#pragma unroll
  for (int off = 32; off > 0; off >>= 1) mx = fmaxf(mx, __shfl_xor(mx, off, 64));
  if ((tid & 63) == 0) red[tid >> 6] = mx;
  __syncthreads();
  mx = fmaxf(fmaxf(red[0], red[1]), fmaxf(red[2], red[3]));

  float sum = 0.f;
#pragma unroll
  for (int i = 0; i < 8; ++i)
    sum += expf(v[i].x - mx) + expf(v[i].y - mx) + expf(v[i].z - mx) + expf(v[i].w - mx);
#pragma unroll
  for (int off = 32; off > 0; off >>= 1) sum += __shfl_xor(sum, off, 64);
  if ((tid & 63) == 0) red2[tid >> 6] = sum;
  __syncthreads();
  sum = (red2[0] + red2[1]) + (red2[2] + red2[3]);

  const float lse = mx + logf(sum);
#pragma unroll
  for (int i = 0; i < 8; ++i) {
    float4 o = v[i];
    o.x -= lse; o.y -= lse; o.z -= lse; o.w -= lse;
    *reinterpret_cast<float4*>(&row[(i * 256 + tid) * 4]) = o;
  }
}

extern "C" void kernel_launch(void* const* d_in, const int* in_sizes, int n_in,
                              void* d_out, int out_size, void* d_ws, size_t ws_size,
                              hipStream_t stream) {
  const int* idx = (const int*)d_in[0];
  const float* h0 = (const float*)d_in[1];
  const float* W_ih = (const float*)d_in[2];
  const float* b_ih = (const float*)d_in[3];
  const float* W_hh = (const float*)d_in[4];
  const float* b_hh = (const float*)d_in[5];
  const float* W_ho = (const float*)d_in[6];
  const float* b_o = (const float*)d_in[7];
  float* out = (float*)d_out;

  // workspace layout (~42.1 MB):
  // X  f32  [128][32][1024]            16777216 B @ 0
  // Hb bf16 [129][32][1024]             8454144 B @ 16777216
  // Wb bf16 [8192][1024]               16777216 B @ 25231360
  // Rb bf16 [1024][1024]                2097152 B @ 42008576
  // Wdiag f32 [1024]                       4096 B @ 44105728
  // bar u32 [2]                            4096 B @ 44109824
  char* ws = (char*)d_ws;
  float* X = (float*)ws;
  short* Hb = (short*)(ws + 16777216);
  short* Wb = (short*)(ws + 25231360);
  short* Rb = (short*)(ws + 42008576);
  float* Wdiag = (float*)(ws + 44105728);
  unsigned* bar = (unsigned*)(ws + 44109824);

  conv_bf16_k<<<dim3(8192), dim3(256), 0, stream>>>(W_ho, Wb, (V_ * D_) / 4);
  conv_whh<<<dim3(4096), dim3(256), 0, stream>>>(W_hh, Rb, Wdiag);
  init_h<<<dim3(128), dim3(256), 0, stream>>>(h0, Hb, bar);
  xgather<<<dim3(16384), dim3(256), 0, stream>>>(idx, W_ih, b_ih, b_hh, X);

  rnn_all<<<dim3(128), dim3(512), 0, stream>>>(Rb, Wdiag, h0, X, Hb, bar);

  // logits for step t read Hb slot t+1  ->  A = Hb + 32768
  gemm_logits<<<dim3(V_ / 128, (T_ * B_) / 128), dim3(256), 0, stream>>>(
      Hb + B_ * D_, Wb, b_o, out);
  logsoftmax<<<dim3(T_ * B_), dim3(256), 0, stream>>>(out);
}

// Round 4
// 821.784 us; speedup vs baseline: 3.2559x; 3.2559x over previous
//
#include <hip/hip_runtime.h>
#include <hip/hip_bf16.h>
#include <cstdint>
#include <cstddef>

#define V_ 8192
#define D_ 1024
#define B_ 32
#define T_ 128
#define NBLK 16

typedef __attribute__((ext_vector_type(8))) short bf16x8;
typedef __attribute__((ext_vector_type(4))) float f32x4;

__device__ __forceinline__ short f2bf(float f) {
  union { float f; unsigned u; } v; v.f = f;
  unsigned r = v.u + 0x7fffu + ((v.u >> 16) & 1u);
  return (short)(r >> 16);
}

__device__ __forceinline__ float bf2f(unsigned short u) {
  union { unsigned u; float f; } c; c.u = ((unsigned)u) << 16;
  return c.f;
}

// async global->LDS, 16B per lane. lds base must be wave-uniform.
__device__ __forceinline__ void lds_load16(const void* g, void* l) {
  __builtin_amdgcn_global_load_lds(
      (const __attribute__((address_space(1))) unsigned int*)g,
      (__attribute__((address_space(3))) unsigned int*)l,
      16, 0, 0);
}

// ---------- f32 -> bf16 conversion ----------
__global__ __launch_bounds__(256) void conv_bf16_k(const float* __restrict__ in,
                                                   short* __restrict__ out, int n4) {
  int i = blockIdx.x * 256 + threadIdx.x;  // one float4 per thread
  if (i >= n4) return;
  float4 v = reinterpret_cast<const float4*>(in)[i];
  short4 o;
  o.x = f2bf(v.x); o.y = f2bf(v.y); o.z = f2bf(v.z); o.w = f2bf(v.w);
  reinterpret_cast<short4*>(out)[i] = o;
}

// ---------- W_hh split: Rb = bf16(W_hh, zero diag), Wdiag = diag(W_hh) f32 ----------
__global__ __launch_bounds__(256) void conv_whh(const float* __restrict__ W,
                                                short* __restrict__ Rb,
                                                float* __restrict__ Wdiag) {
  int i = blockIdx.x * 256 + threadIdx.x;   // over D*D = 1048576
  int n = i >> 10;
  int k = i & (D_ - 1);
  float w = W[i];
  Rb[i] = f2bf(k == n ? 0.0f : w);
  if (k == n) Wdiag[n] = w;
}

// ---------- h0 -> Hb slot0 (bf16); zero barrier flags ----------
__global__ __launch_bounds__(256) void init_h(const float* __restrict__ h0,
                                              short* __restrict__ Hb0,
                                              unsigned* __restrict__ flags) {
  int i = blockIdx.x * 256 + threadIdx.x;   // over 32768
  Hb0[i] = f2bf(h0[i]);
  if (i < 64) flags[i] = 0u;
}

// ---------- Wtb[v][d] = bf16(W_ih[d][v] + b_ih[d] + b_hh[d]) ----------
// tiled 32x32 transpose, block 256 (32x8), grid (V/32, D/32)
__global__ __launch_bounds__(256) void wtrans(const float* __restrict__ W,
                                              const float* __restrict__ b_ih,
                                              const float* __restrict__ b_hh,
                                              short* __restrict__ Wtb) {
  __shared__ float tile[32][33];
  const int tx = threadIdx.x & 31;
  const int ty = threadIdx.x >> 5;          // 0..7
  const int v0 = blockIdx.x * 32;
  const int d0 = blockIdx.y * 32;
#pragma unroll
  for (int i = 0; i < 32; i += 8)
    tile[ty + i][tx] = W[(size_t)(d0 + ty + i) * V_ + v0 + tx];
  __syncthreads();
  const int d = d0 + tx;
  const float bias = b_ih[d] + b_hh[d];
#pragma unroll
  for (int i = 0; i < 32; i += 8)
    Wtb[(size_t)(v0 + ty + i) * D_ + d] = f2bf(tile[tx][ty + i] + bias);
}

// ---------- persistent recurrence: all 128 steps, 16 blocks x 8 waves ----------
// block: n-tile of 64 (n0 = blk*64), all 32 batch rows.
// wave w: K-slice [w*128, w*128+128); Rb fragments persistent in VGPRs.
// epilogue: wave w owns output tile (mi=w>>2, ni=w&3) of 16x16; diag state hf
// and X-gather live in that wave's registers for all 128 steps.
__global__ __launch_bounds__(512) void rnn_all(const short* __restrict__ Rb,
                                               const float* __restrict__ Wdiag,
                                               const float* __restrict__ h0,
                                               const short* __restrict__ Wtb,
                                               const int* __restrict__ idx,
                                               short* __restrict__ Hb,
                                               unsigned* __restrict__ flags) {
  const int tid = threadIdx.x;
  const int lane = tid & 63;
  const int w = tid >> 6;                  // 0..7, wave-uniform
  const int n0 = blockIdx.x * 64;
  const int fcol = lane & 15;
  const int l16 = lane >> 4;               // 0..3
  const int ks = w * 128;

  __shared__ f32x4 part[8][2][4][64];      // 64 KB

  // persistent B fragments: Rb rows n0..n0+63, this wave's K-slice (64 VGPRs)
  bf16x8 bfrag[4][4];
#pragma unroll
  for (int ni = 0; ni < 4; ++ni) {
    const short* bp = Rb + (size_t)(n0 + ni * 16 + fcol) * D_ + ks + l16 * 8;
#pragma unroll
    for (int kk = 0; kk < 4; ++kk)
      bfrag[ni][kk] = *reinterpret_cast<const bf16x8*>(bp + kk * 32);
  }

  // epilogue role: fixed (m,n) ownership across all steps
  const int mi_e = w >> 2;                 // 0..1
  const int ni_e = w & 3;                  // 0..3
  const int n_e = n0 + ni_e * 16 + fcol;
  const int mbase = mi_e * 16 + l16 * 4;   // +q -> batch row
  const float wd = Wdiag[n_e];
  float hf[4];
#pragma unroll
  for (int q = 0; q < 4; ++q)
    hf[q] = h0[(size_t)(mbase + q) * D_ + n_e];

  for (int t = 0; t < T_; ++t) {
    // X gather for this step (issued first; used only in epilogue)
    float xv[4];
#pragma unroll
    for (int q = 0; q < 4; ++q) {
      int tok = idx[(mbase + q) * T_ + t];
      xv[q] = bf2f(*reinterpret_cast<const unsigned short*>(
          Wtb + (size_t)tok * D_ + n_e));
    }

    // A fragments from Hb slot t
    const short* hp = Hb + (size_t)t * (B_ * D_);
    bf16x8 af[2][4];
#pragma unroll
    for (int mi = 0; mi < 2; ++mi) {
      const short* ap = hp + (size_t)(mi * 16 + fcol) * D_ + ks + l16 * 8;
#pragma unroll
      for (int kk = 0; kk < 4; ++kk)
        af[mi][kk] = *reinterpret_cast<const bf16x8*>(ap + kk * 32);
    }

#pragma unroll
    for (int mi = 0; mi < 2; ++mi)
#pragma unroll
      for (int ni = 0; ni < 4; ++ni) {
        f32x4 a = {0.f, 0.f, 0.f, 0.f};
#pragma unroll
        for (int kk = 0; kk < 4; ++kk)
          a = __builtin_amdgcn_mfma_f32_16x16x32_bf16(af[mi][kk], bfrag[ni][kk], a, 0, 0, 0);
        part[w][mi][ni][lane] = a;
      }
    __syncthreads();

    // reduce this wave's tile across the 8 K-slices
    f32x4 s = part[0][mi_e][ni_e][lane];
#pragma unroll
    for (int r = 1; r < 8; ++r) s += part[r][mi_e][ni_e][lane];

    short* hn = Hb + (size_t)(t + 1) * (B_ * D_);
#pragma unroll
    for (int q = 0; q < 4; ++q) {
      float v = tanhf(xv[q] + s[q] + hf[q] * wd);
      hf[q] = v;
      hn[(size_t)(mbase + q) * D_ + n_e] = f2bf(v);
    }

    if (t < T_ - 1) {
      __syncthreads();   // drains vmcnt: all waves' h-stores are in L2
      if (tid == 0) {
        __builtin_amdgcn_fence(__ATOMIC_RELEASE, "agent");       // wbl2: flush h to L3
        __hip_atomic_store(flags + blockIdx.x, (unsigned)(t + 1),
                           __ATOMIC_RELEASE, __HIP_MEMORY_SCOPE_AGENT);
      }
      if (w == 0) {
        const unsigned gen = (unsigned)(t + 1);
        while (true) {
          unsigned f = gen;
          if (lane < NBLK)
            f = __hip_atomic_load(flags + lane, __ATOMIC_RELAXED,
                                  __HIP_MEMORY_SCOPE_AGENT);
          if (__all(f >= gen)) break;
          __builtin_amdgcn_s_sleep(1);
        }
      }
      __syncthreads();
      __builtin_amdgcn_fence(__ATOMIC_ACQUIRE, "agent");         // inv L1/L2
    }
  }
}

// ---------- logits GEMM: C[r, v] = sum_d Hb[r,d]*Wb[v,d] + b_o[v] ----------
// M=4096, N=8192, K=1024. bf16 MFMA 16x16x32, tile 128x128, BK=64, 4 waves.
// LDS XOR-swizzle: chunk col ^= (row&7), applied on global SOURCE + ds_read index.
__global__ __launch_bounds__(256) void gemm_logits(const short* __restrict__ A,
                                                   const short* __restrict__ Bt,
                                                   const float* __restrict__ b_o,
                                                   float* __restrict__ C) {
  constexpr int K = D_;
  constexpr int N = V_;
  __shared__ __align__(16) short As[128 * 64];  // 16 KB, [128][8 chunks of 8 bf16]
  __shared__ __align__(16) short Bs[128 * 64];

  const int tid = threadIdx.x;
  const int lane = tid & 63;
  const int w = tid >> 6;
  const int wr = w >> 1, wc = w & 1;
  const int r0 = blockIdx.y * 128;
  const int c0 = blockIdx.x * 128;

  f32x4 acc[4][4] = {};

  for (int k0 = 0; k0 < K; k0 += 64) {
#pragma unroll
    for (int i = 0; i < 4; ++i) {
      int c = tid + 256 * i;                 // per-lane chunk id
      int cb = (tid & ~63) + 256 * i;        // wave-uniform chunk base
      int row = c >> 3;
      int colc = ((c & 7) ^ (row & 7)) * 8;  // pre-swizzled source column
      lds_load16(A + (size_t)(r0 + row) * K + k0 + colc, &As[cb * 8]);
      lds_load16(Bt + (size_t)(c0 + row) * K + k0 + colc, &Bs[cb * 8]);
    }
    asm volatile("s_waitcnt vmcnt(0)" ::: "memory");
    __syncthreads();

#pragma unroll
    for (int kk = 0; kk < 2; ++kk) {
      bf16x8 af[4], bfr[4];
      const int fcol = lane & 15;
      const int chunk = (kk * 4 + (lane >> 4)) ^ (fcol & 7);  // swizzled read chunk
#pragma unroll
      for (int i = 0; i < 4; ++i)
        af[i] = *reinterpret_cast<const bf16x8*>(&As[(wr * 64 + i * 16 + fcol) * 64 + chunk * 8]);
#pragma unroll
      for (int j = 0; j < 4; ++j)
        bfr[j] = *reinterpret_cast<const bf16x8*>(&Bs[(wc * 64 + j * 16 + fcol) * 64 + chunk * 8]);
#pragma unroll
      for (int i = 0; i < 4; ++i)
#pragma unroll
        for (int j = 0; j < 4; ++j)
          acc[i][j] = __builtin_amdgcn_mfma_f32_16x16x32_bf16(af[i], bfr[j], acc[i][j], 0, 0, 0);
    }
    __syncthreads();
  }

  const int fcol = lane & 15;
  const int frow = (lane >> 4) * 4;
#pragma unroll
  for (int i = 0; i < 4; ++i) {
    int row = r0 + wr * 64 + i * 16 + frow;
#pragma unroll
    for (int j = 0; j < 4; ++j) {
      int col = c0 + wc * 64 + j * 16 + fcol;
      float bias = b_o[col];
#pragma unroll
      for (int q = 0; q < 4; ++q)
        C[(size_t)(row + q) * N + col] = acc[i][j][q] + bias;
    }
  }
}

// ---------- in-place log-softmax over rows of 8192 ----------
__global__ __launch_bounds__(256) void logsoftmax(float* __restrict__ out) {
  __shared__ float red[4];
  __shared__ float red2[4];
  float* row = out + (size_t)blockIdx.x * V_;
  const int tid = threadIdx.x;

  float4 v[8];
  float mx = -1e30f;
#pragma unroll
  for (int i = 0; i < 8; ++i) {
    v[i] = *reinterpret_cast<const float4*>(&row[(i * 256 + tid) * 4]);
    mx = fmaxf(mx, fmaxf(fmaxf(v[i].x, v[i].y), fmaxf(v[i].z, v[i].w)));
  }
#pragma unroll
  for (int off = 32; off > 0; off >>= 1) mx = fmaxf(mx, __shfl_xor(mx, off, 64));
  if ((tid & 63) == 0) red[tid >> 6] = mx;
  __syncthreads();
  mx = fmaxf(fmaxf(red[0], red[1]), fmaxf(red[2], red[3]));

  float sum = 0.f;
#pragma unroll
  for (int i = 0; i < 8; ++i)
    sum += expf(v[i].x - mx) + expf(v[i].y - mx) + expf(v[i].z - mx) + expf(v[i].w - mx);
#pragma unroll
  for (int off = 32; off > 0; off >>= 1) sum += __shfl_xor(sum, off, 64);
  if ((tid & 63) == 0) red2[tid >> 6] = sum;
  __syncthreads();
  sum = (red2[0] + red2[1]) + (red2[2] + red2[3]);

  const float lse = mx + logf(sum);
#pragma unroll
  for (int i = 0; i < 8; ++i) {
    float4 o = v[i];
    o.x -= lse; o.y -= lse; o.z -= lse; o.w -= lse;
    *reinterpret_cast<float4*>(&row[(i * 256 + tid) * 4]) = o;
  }
}

extern "C" void kernel_launch(void* const* d_in, const int* in_sizes, int n_in,
                              void* d_out, int out_size, void* d_ws, size_t ws_size,
                              hipStream_t stream) {
  const int* idx = (const int*)d_in[0];
  const float* h0 = (const float*)d_in[1];
  const float* W_ih = (const float*)d_in[2];
  const float* b_ih = (const float*)d_in[3];
  const float* W_hh = (const float*)d_in[4];
  const float* b_hh = (const float*)d_in[5];
  const float* W_ho = (const float*)d_in[6];
  const float* b_o = (const float*)d_in[7];
  float* out = (float*)d_out;

  // workspace layout (~44.1 MB):
  // Hb  bf16 [129][32][1024]   8454144 B @ 0
  // Wb  bf16 [8192][1024]     16777216 B @ 8454144
  // Rb  bf16 [1024][1024]      2097152 B @ 25231360
  // Wdiag f32 [1024]              4096 B @ 27328512
  // Wtb bf16 [8192][1024]     16777216 B @ 27332608
  // flags u32 [64]                 256 B @ 44109824
  char* ws = (char*)d_ws;
  short* Hb = (short*)ws;
  short* Wb = (short*)(ws + 8454144);
  short* Rb = (short*)(ws + 25231360);
  float* Wdiag = (float*)(ws + 27328512);
  short* Wtb = (short*)(ws + 27332608);
  unsigned* flags = (unsigned*)(ws + 44109824);

  conv_bf16_k<<<dim3(8192), dim3(256), 0, stream>>>(W_ho, Wb, (V_ * D_) / 4);
  conv_whh<<<dim3(4096), dim3(256), 0, stream>>>(W_hh, Rb, Wdiag);
  init_h<<<dim3(128), dim3(256), 0, stream>>>(h0, Hb, flags);
  wtrans<<<dim3(V_ / 32, D_ / 32), dim3(256), 0, stream>>>(W_ih, b_ih, b_hh, Wtb);

  rnn_all<<<dim3(NBLK), dim3(512), 0, stream>>>(Rb, Wdiag, h0, Wtb, idx, Hb, flags);

  // logits for step t read Hb slot t+1  ->  A = Hb + 32768
  gemm_logits<<<dim3(V_ / 128, (T_ * B_) / 128), dim3(256), 0, stream>>>(
      Hb + B_ * D_, Wb, b_o, out);
  logsoftmax<<<dim3(T_ * B_), dim3(256), 0, stream>>>(out);
}